// Round 5
// baseline (76564.215 us; speedup 1.0000x reference)
//
#include <hip/hip_runtime.h>

// AlternatingForecastModel: 2-layer LSTM (H=512) over S=2688 steps, B=512.
// Persistent cooperative kernel: 256 wgs x 512 thr. 4 batch-groups(128 rows) x 64 hidden-shards(8 units).
// Weights fp16 in LDS (XOR-swizzled), fp16 MFMA w/ fp32 accum, fp32 c-state in LDS.
// h0/h1 exchanged via fp16 global buffers (d_ws); custom per-group barriers (monotonic counter).
// Cooperative launch guarantees co-residency (or fails loudly) -> spin barriers cannot deadlock.

#define BB 512
#define SS 2688
#define FF 32
#define HH 512
#define WEEK 672
#define ROWS 128   // rows per batch-group
#define HS 8       // hidden units per shard
#define GR 32      // gate rows per shard per layer (4*HS)
#define NWPG 64    // workgroups per group

typedef _Float16 f16x8 __attribute__((ext_vector_type(8)));
typedef float f32x4 __attribute__((ext_vector_type(4)));

__device__ __forceinline__ float sigf(float x) { return 1.0f / (1.0f + __expf(-x)); }
__device__ __forceinline__ float tanhfast(float x) { return 1.0f - 2.0f / (__expf(2.0f * x) + 1.0f); }

__device__ __forceinline__ void group_barrier(unsigned* cnt, unsigned ticket) {
  __syncthreads();
  if (threadIdx.x == 0) {
    __builtin_amdgcn_fence(__ATOMIC_RELEASE, "agent");
    __hip_atomic_fetch_add(cnt, 1u, __ATOMIC_RELAXED, __HIP_MEMORY_SCOPE_AGENT);
    const unsigned tgt = ticket * NWPG;
    while (__hip_atomic_load(cnt, __ATOMIC_RELAXED, __HIP_MEMORY_SCOPE_AGENT) < tgt) {
      __builtin_amdgcn_s_sleep(1);
    }
    __builtin_amdgcn_fence(__ATOMIC_ACQUIRE, "agent");
  }
  __syncthreads();
}

__global__ __launch_bounds__(512, 2) void lstm_persist(
    const float* __restrict__ x,
    const float* __restrict__ Wih0, const float* __restrict__ Whh0,
    const float* __restrict__ bih0, const float* __restrict__ bhh0,
    const float* __restrict__ Wih1, const float* __restrict__ Whh1,
    const float* __restrict__ bih1, const float* __restrict__ bhh1,
    const float* __restrict__ Wout, const float* __restrict__ bout,
    float* __restrict__ out, _Float16* __restrict__ h0buf, _Float16* __restrict__ h1buf,
    unsigned* __restrict__ barcnt)
{
  // LDS: weights swizzled so B-fragment ds_read_b128 spreads banks (T2/G4).
  __shared__ _Float16 w0[GR][576];    // [i0..7,f0..7,g0..7,o0..7] x (64 padded input cols | 512 Whh0)
  __shared__ _Float16 w1[GR][1024];   // (512 Wih1 | 512 Whh1)
  __shared__ _Float16 curt[ROWS][64]; // per-step input tile (feat0, x1..31, flag, pad)
  __shared__ float c0s[ROWS][HS];
  __shared__ float c1s[ROWS][HS];
  __shared__ float bias0[GR], bias1[GR], wouts[HS], boutv;

  const int tid = threadIdx.x;
  const int bid = blockIdx.x;
  const int xcd = bid & 7;
  const int grp = xcd >> 1;                           // 0..3: batch group (co-located on XCD pair)
  const int shard = ((bid >> 3) << 1) | (xcd & 1);    // 0..63: hidden shard
  const int Rg = grp * ROWS;
  const int U0 = shard * HS;
  unsigned* cnt = barcnt + grp * 64;                  // 256B apart

  // ---- one-time weight staging (fp32 -> fp16, swizzled) ----
  for (int idx = tid; idx < GR * 576; idx += 512) {
    int rrow = idx / 576, col = idx % 576;
    int gt = rrow >> 3, un = rrow & 7;
    int grow = gt * 512 + U0 + un;
    float v;
    if (col < 33)      v = Wih0[grow * 33 + col];
    else if (col < 64) v = 0.f;
    else               v = Whh0[(size_t)grow * 512 + (col - 64)];
    int sc = (((col >> 3) ^ (rrow & 7)) << 3) | (col & 7);
    w0[rrow][sc] = (_Float16)v;
  }
  for (int idx = tid; idx < GR * 1024; idx += 512) {
    int rrow = idx >> 10, col = idx & 1023;
    int gt = rrow >> 3, un = rrow & 7;
    int grow = gt * 512 + U0 + un;
    float v = (col < 512) ? Wih1[(size_t)grow * 512 + col]
                          : Whh1[(size_t)grow * 512 + (col - 512)];
    int sc = (((col >> 3) ^ (rrow & 7)) << 3) | (col & 7);
    w1[rrow][sc] = (_Float16)v;
  }
  if (tid < GR) {
    int gt = tid >> 3, un = tid & 7;
    int grow = gt * 512 + U0 + un;
    bias0[tid] = bih0[grow] + bhh0[grow];
    bias1[tid] = bih1[grow] + bhh1[grow];
  }
  if (tid < HS) wouts[tid] = Wout[U0 + tid];
  if (tid == 0) boutv = bout[0];
  for (int idx = tid; idx < ROWS * HS; idx += 512) {
    ((float*)c0s)[idx] = 0.f; ((float*)c1s)[idx] = 0.f;
  }
  __syncthreads();

  const int lane = tid & 63;
  const int wv = tid >> 6;       // wave 0..7, owns 16 rows
  const int Rw = wv * 16;
  const int r16 = lane & 15;
  const int kq = lane >> 4;      // 0..3
  const int ulane = lane & 7;
  const bool lo8 = (lane & 8) == 0;

  unsigned bticket = 0;

  for (int t = 0; t < SS; ++t) {
    const int tw = t / WEEK;
    const bool use_orig = ((tw & 1) == 0);   // S = exactly 4 weeks, so (tw+1)*WEEK <= S always
    // ---- build current-input tile (4 threads per row) ----
    {
      int row = tid >> 2, q = tid & 3;
      const int growx = Rg + row;
      f16x8 vlo, vhi;
      if (q < 2) {
        const float* xp = x + ((size_t)growx * SS + t) * FF + q * 16;
        float tmp[16];
        #pragma unroll
        for (int j = 0; j < 16; ++j) tmp[j] = xp[j];
        if (q == 0 && !use_orig) tmp[0] = out[(size_t)growx * SS + (t - 1)];  // prev_pred feedback
        #pragma unroll
        for (int j = 0; j < 8; ++j) { vlo[j] = (_Float16)tmp[j]; vhi[j] = (_Float16)tmp[8 + j]; }
      } else {
        #pragma unroll
        for (int j = 0; j < 8; ++j) { vlo[j] = (_Float16)0.f; vhi[j] = (_Float16)0.f; }
        if (q == 2) vlo[0] = (_Float16)(use_orig ? 0.f : 1.f);   // flag at col 32
      }
      int b0 = (q * 2) ^ (row & 7), b1 = (q * 2 + 1) ^ (row & 7);
      *(f16x8*)&curt[row][b0 << 3] = vlo;
      *(f16x8*)&curt[row][b1 << 3] = vhi;
    }
    __syncthreads();

    // ---- phase 0: layer0 ----
    {
      f32x4 acc0 = {0,0,0,0}, acc1 = {0,0,0,0};
      const int arow = Rw + r16;
      #pragma unroll
      for (int kt = 0; kt < 2; ++kt) {
        int ab = (((kt * 4 + kq) ^ (arow & 7)) << 3);
        f16x8 a = *(const f16x8*)&curt[arow][ab];
        int bo = (((kt * 4 + kq) ^ (r16 & 7)) << 3);
        f16x8 b0 = *(const f16x8*)&w0[r16][bo];
        f16x8 b1 = *(const f16x8*)&w0[16 + r16][bo];
        acc0 = __builtin_amdgcn_mfma_f32_16x16x32_f16(a, b0, acc0, 0, 0, 0);
        acc1 = __builtin_amdgcn_mfma_f32_16x16x32_f16(a, b1, acc1, 0, 0, 0);
      }
      if (t > 0) {
        const _Float16* hp = h0buf + (size_t)((t - 1) & 1) * BB * HH + (size_t)(Rg + arow) * HH + kq * 8;
        #pragma unroll 8
        for (int kt = 0; kt < 16; ++kt) {
          f16x8 a = *(const f16x8*)(hp + kt * 32);
          int bo = (((8 + kt * 4 + kq) ^ (r16 & 7)) << 3);
          f16x8 b0 = *(const f16x8*)&w0[r16][bo];
          f16x8 b1 = *(const f16x8*)&w0[16 + r16][bo];
          acc0 = __builtin_amdgcn_mfma_f32_16x16x32_f16(a, b0, acc0, 0, 0, 0);
          acc1 = __builtin_amdgcn_mfma_f32_16x16x32_f16(a, b1, acc1, 0, 0, 0);
        }
      }
      float bi0 = bias0[r16], bi1 = bias0[16 + r16];
      #pragma unroll
      for (int rr = 0; rr < 4; ++rr) {
        float p0 = acc0[rr] + bi0, p1 = acc1[rr] + bi1;
        float q0 = __shfl_xor(p0, 8), q1 = __shfl_xor(p1, 8);
        float iv = lo8 ? p0 : q0, fv = lo8 ? q0 : p0;
        float gv = lo8 ? p1 : q1, ov = lo8 ? q1 : p1;
        int row = Rw + kq * 4 + rr;
        float cold = (t == 0) ? 0.f : c0s[row][ulane];
        float cn = sigf(fv) * cold + sigf(iv) * tanhfast(gv);
        float hn = sigf(ov) * tanhfast(cn);
        if (lo8) {
          c0s[row][ulane] = cn;
          h0buf[(size_t)(t & 1) * BB * HH + (size_t)(Rg + row) * HH + U0 + ulane] = (_Float16)hn;
        }
      }
    }
    group_barrier(cnt, ++bticket);   // h0[t] visible group-wide

    // ---- phase 1: layer1 + output ----
    {
      f32x4 acc0 = {0,0,0,0}, acc1 = {0,0,0,0};
      const int arow = Rw + r16;
      const _Float16* h0c = h0buf + (size_t)(t & 1) * BB * HH + (size_t)(Rg + arow) * HH + kq * 8;
      #pragma unroll 8
      for (int kt = 0; kt < 16; ++kt) {
        f16x8 a = *(const f16x8*)(h0c + kt * 32);
        int bo = (((kt * 4 + kq) ^ (r16 & 7)) << 3);
        f16x8 b0 = *(const f16x8*)&w1[r16][bo];
        f16x8 b1 = *(const f16x8*)&w1[16 + r16][bo];
        acc0 = __builtin_amdgcn_mfma_f32_16x16x32_f16(a, b0, acc0, 0, 0, 0);
        acc1 = __builtin_amdgcn_mfma_f32_16x16x32_f16(a, b1, acc1, 0, 0, 0);
      }
      if (t > 0) {
        const _Float16* h1p = h1buf + (size_t)((t - 1) & 1) * BB * HH + (size_t)(Rg + arow) * HH + kq * 8;
        #pragma unroll 8
        for (int kt = 0; kt < 16; ++kt) {
          f16x8 a = *(const f16x8*)(h1p + kt * 32);
          int bo = (((64 + kt * 4 + kq) ^ (r16 & 7)) << 3);
          f16x8 b0 = *(const f16x8*)&w1[r16][bo];
          f16x8 b1 = *(const f16x8*)&w1[16 + r16][bo];
          acc0 = __builtin_amdgcn_mfma_f32_16x16x32_f16(a, b0, acc0, 0, 0, 0);
          acc1 = __builtin_amdgcn_mfma_f32_16x16x32_f16(a, b1, acc1, 0, 0, 0);
        }
      }
      float bi0 = bias1[r16], bi1 = bias1[16 + r16];
      #pragma unroll
      for (int rr = 0; rr < 4; ++rr) {
        float p0 = acc0[rr] + bi0, p1 = acc1[rr] + bi1;
        float q0 = __shfl_xor(p0, 8), q1 = __shfl_xor(p1, 8);
        float iv = lo8 ? p0 : q0, fv = lo8 ? q0 : p0;
        float gv = lo8 ? p1 : q1, ov = lo8 ? q1 : p1;
        int row = Rw + kq * 4 + rr;
        float cold = (t == 0) ? 0.f : c1s[row][ulane];
        float cn = sigf(fv) * cold + sigf(iv) * tanhfast(gv);
        float hn = sigf(ov) * tanhfast(cn);
        float pv = 0.f;
        if (lo8) {
          c1s[row][ulane] = cn;
          h1buf[(size_t)(t & 1) * BB * HH + (size_t)(Rg + row) * HH + U0 + ulane] = (_Float16)hn;
          pv = hn * wouts[ulane];
        }
        pv += __shfl_xor(pv, 1);
        pv += __shfl_xor(pv, 2);
        pv += __shfl_xor(pv, 4);
        if ((lane & 15) == 0) {
          atomicAdd(&out[(size_t)(Rg + row) * SS + t], pv + (shard == 0 ? boutv : 0.f));
        }
      }
    }
    group_barrier(cnt, ++bticket);   // h1[t] + out[t] visible
  }
}

extern "C" void kernel_launch(void* const* d_in, const int* in_sizes, int n_in,
                              void* d_out, int out_size, void* d_ws, size_t ws_size,
                              hipStream_t stream) {
  const float* x    = (const float*)d_in[0];
  const float* Wih0 = (const float*)d_in[1];
  const float* Whh0 = (const float*)d_in[2];
  const float* bih0 = (const float*)d_in[3];
  const float* bhh0 = (const float*)d_in[4];
  const float* Wih1 = (const float*)d_in[5];
  const float* Whh1 = (const float*)d_in[6];
  const float* bih1 = (const float*)d_in[7];
  const float* bhh1 = (const float*)d_in[8];
  const float* Wout = (const float*)d_in[9];
  const float* bout = (const float*)d_in[10];
  float* out = (float*)d_out;

  // workspace layout: h0buf (1MB) | h1buf (1MB) | barrier counters (1KB)
  const size_t hbytes = (size_t)2 * BB * HH * sizeof(_Float16);
  _Float16* h0buf = (_Float16*)d_ws;
  _Float16* h1buf = (_Float16*)((char*)d_ws + hbytes);
  unsigned* barcnt = (unsigned*)((char*)d_ws + 2 * hbytes);

  // out is atomically accumulated; barrier counters are monotonic from 0.
  hipMemsetAsync(d_out, 0, (size_t)out_size * sizeof(float), stream);
  hipMemsetAsync(barcnt, 0, 4 * 64 * sizeof(unsigned), stream);

  // Cooperative launch: guarantees all 256 wgs co-resident (or errors), so the
  // inter-wg spin barriers cannot deadlock-hang the device.
  void* args[] = {
      (void*)&x, (void*)&Wih0, (void*)&Whh0, (void*)&bih0, (void*)&bhh0,
      (void*)&Wih1, (void*)&Whh1, (void*)&bih1, (void*)&bhh1,
      (void*)&Wout, (void*)&bout, (void*)&out, (void*)&h0buf, (void*)&h1buf,
      (void*)&barcnt};
  hipLaunchCooperativeKernel((const void*)lstm_persist, dim3(256), dim3(512),
                             args, 0, stream);
}

// Round 8
// 55718.164 us; speedup vs baseline: 1.3741x; 1.3741x over previous
//
#include <hip/hip_runtime.h>

// AlternatingForecastModel: 2-layer LSTM (H=512) over S=2688 steps, B=512.
// Persistent cooperative kernel: 256 wgs x 512 thr. 4 batch-groups(128 rows) x 64 hidden-shards(8 units).
// Weights fp16 in LDS (+8-f16 row pad, bank-conflict-free), fp16 MFMA w/ fp32 accum, fp32 c-state in LDS.
// h0/h1 exchanged via sc0+sc1 (L3-coherent, L1/L2-bypass) loads/stores -> NO agent fences, L2 never
// invalidated. Barrier = vmcnt(0) drain + relaxed agent RMW + spin (construct HW-proven in round 5).

#define BB 512
#define SS 2688
#define FF 32
#define HH 512
#define WEEK 672
#define ROWS 128   // rows per batch-group
#define HS 8       // hidden units per shard
#define GR 32      // gate rows per shard per layer (4*HS)
#define NWPG 64    // workgroups per group

typedef _Float16 f16x8 __attribute__((ext_vector_type(8)));
typedef float f32x4 __attribute__((ext_vector_type(4)));

__device__ __forceinline__ float sigf(float x) { return 1.0f / (1.0f + __expf(-x)); }
__device__ __forceinline__ float tanhfast(float x) { return 1.0f - 2.0f / (__expf(2.0f * x) + 1.0f); }

// L3-coherent accessors: sc0 sc1 = bypass L1 and L2, operate at device coherence point.
#define LDX4(dst, base, off) \
  asm volatile("global_load_dwordx4 %0, %1, off offset:%2 sc0 sc1" : "=v"(dst) : "v"(base), "n"(off) : "memory")
#define STH(base, val, off) \
  asm volatile("global_store_short %0, %1, off offset:%2 sc0 sc1" :: "v"(base), "v"(val), "n"(off) : "memory")
#define WAIT_VM0() asm volatile("s_waitcnt vmcnt(0)" ::: "memory")

__device__ __forceinline__ void group_barrier(unsigned* cnt, unsigned ticket) {
  WAIT_VM0();                    // every wave drains its sc0sc1 stores + atomics to coherence point
  __syncthreads();
  if (threadIdx.x == 0) {
    __hip_atomic_fetch_add(cnt, 1u, __ATOMIC_RELAXED, __HIP_MEMORY_SCOPE_AGENT);
    const unsigned tgt = ticket * NWPG;
    while (__hip_atomic_load(cnt, __ATOMIC_RELAXED, __HIP_MEMORY_SCOPE_AGENT) < tgt) {
      __builtin_amdgcn_s_sleep(1);
    }
  }
  __syncthreads();               // no acquire fence: post-barrier reads are sc0 sc1 (L2-bypassing)
}

__global__ __launch_bounds__(512, 2) void lstm_persist(
    const float* __restrict__ x,
    const float* __restrict__ Wih0, const float* __restrict__ Whh0,
    const float* __restrict__ bih0, const float* __restrict__ bhh0,
    const float* __restrict__ Wih1, const float* __restrict__ Whh1,
    const float* __restrict__ bih1, const float* __restrict__ bhh1,
    const float* __restrict__ Wout, const float* __restrict__ bout,
    float* __restrict__ out, _Float16* __restrict__ h0buf, _Float16* __restrict__ h1buf,
    unsigned* __restrict__ barcnt)
{
  // +8 f16 row pad: row strides 1184/2064/144 B -> bank quad = (row+block)&7, no >2-way conflicts.
  __shared__ _Float16 w0[GR][584];    // [i0..7,f0..7,g0..7,o0..7] x (64 padded input cols | 512 Whh0)
  __shared__ _Float16 w1[GR][1032];   // (512 Wih1 | 512 Whh1)
  __shared__ _Float16 curt[ROWS][72]; // per-step input tile (feat0, x1..31, flag, pad)
  __shared__ float c0s[ROWS][HS];
  __shared__ float c1s[ROWS][HS];
  __shared__ float bias0[GR], bias1[GR], wouts[HS], boutv;

  const int tid = threadIdx.x;
  const int bid = blockIdx.x;
  const int xcd = bid & 7;
  const int grp = xcd >> 1;                           // 0..3: batch group (co-located on XCD pair)
  const int shard = ((bid >> 3) << 1) | (xcd & 1);    // 0..63: hidden shard
  const int Rg = grp * ROWS;
  const int U0 = shard * HS;
  unsigned* cnt = barcnt + grp * 64;                  // 256B apart

  // ---- one-time weight staging (fp32 -> fp16, linear layout) ----
  for (int idx = tid; idx < GR * 576; idx += 512) {
    int rrow = idx / 576, col = idx % 576;
    int gt = rrow >> 3, un = rrow & 7;
    int grow = gt * 512 + U0 + un;
    float v;
    if (col < 33)      v = Wih0[grow * 33 + col];
    else if (col < 64) v = 0.f;
    else               v = Whh0[(size_t)grow * 512 + (col - 64)];
    w0[rrow][col] = (_Float16)v;
  }
  for (int idx = tid; idx < GR * 1024; idx += 512) {
    int rrow = idx >> 10, col = idx & 1023;
    int gt = rrow >> 3, un = rrow & 7;
    int grow = gt * 512 + U0 + un;
    float v = (col < 512) ? Wih1[(size_t)grow * 512 + col]
                          : Whh1[(size_t)grow * 512 + (col - 512)];
    w1[rrow][col] = (_Float16)v;
  }
  if (tid < GR) {
    int gt = tid >> 3, un = tid & 7;
    int grow = gt * 512 + U0 + un;
    bias0[tid] = bih0[grow] + bhh0[grow];
    bias1[tid] = bih1[grow] + bhh1[grow];
  }
  if (tid < HS) wouts[tid] = Wout[U0 + tid];
  if (tid == 0) boutv = bout[0];
  for (int idx = tid; idx < ROWS * HS; idx += 512) {
    ((float*)c0s)[idx] = 0.f; ((float*)c1s)[idx] = 0.f;
  }
  __syncthreads();

  const int lane = tid & 63;
  const int wv = tid >> 6;       // wave 0..7, owns 16 rows
  const int Rw = wv * 16;
  const int r16 = lane & 15;
  const int kq = lane >> 4;      // 0..3
  const int ulane = lane & 7;
  const bool lo8 = (lane & 8) == 0;

  unsigned bticket = 0;

  for (int t = 0; t < SS; ++t) {
    const int tw = t / WEEK;
    const bool use_orig = ((tw & 1) == 0);   // S = exactly 4 weeks, so (tw+1)*WEEK <= S always
    // ---- build current-input tile (4 threads per row) ----
    {
      int row = tid >> 2, q = tid & 3;
      const int growx = Rg + row;
      f16x8 vlo, vhi;
      if (q < 2) {
        const float* xp = x + ((size_t)growx * SS + t) * FF + q * 16;
        float tmp[16];
        #pragma unroll
        for (int j = 0; j < 16; ++j) tmp[j] = xp[j];
        if (q == 0 && !use_orig) {
          // prev_pred feedback: out[] accumulated via device atomics -> L3-coherent read
          const float* pp = out + (size_t)growx * SS + (t - 1);
          float r;
          asm volatile("global_load_dword %0, %1, off sc0 sc1\n\ts_waitcnt vmcnt(0)"
                       : "=v"(r) : "v"(pp) : "memory");
          tmp[0] = r;
        }
        #pragma unroll
        for (int j = 0; j < 8; ++j) { vlo[j] = (_Float16)tmp[j]; vhi[j] = (_Float16)tmp[8 + j]; }
      } else {
        #pragma unroll
        for (int j = 0; j < 8; ++j) { vlo[j] = (_Float16)0.f; vhi[j] = (_Float16)0.f; }
        if (q == 2) vlo[0] = (_Float16)(use_orig ? 0.f : 1.f);   // flag at col 32
      }
      *(f16x8*)&curt[row][(q * 2) << 3]     = vlo;
      *(f16x8*)&curt[row][(q * 2 + 1) << 3] = vhi;
    }
    __syncthreads();

    // ---- phase 0: layer0 ----
    {
      f32x4 acc0 = {0,0,0,0}, acc1 = {0,0,0,0};
      const int arow = Rw + r16;
      if (t > 0) {
        const _Float16* hp = h0buf + (size_t)((t - 1) & 1) * BB * HH + (size_t)(Rg + arow) * HH + kq * 8;
        f16x8 ha[16];
        #pragma unroll
        for (int kt = 0; kt < 16; ++kt) LDX4(ha[kt], hp, kt * 64);
        // x-part MFMAs from LDS overlap the in-flight h loads
        #pragma unroll
        for (int kt = 0; kt < 2; ++kt) {
          f16x8 a  = *(const f16x8*)&curt[arow][(kt * 4 + kq) << 3];
          f16x8 b0 = *(const f16x8*)&w0[r16][(kt * 4 + kq) << 3];
          f16x8 b1 = *(const f16x8*)&w0[16 + r16][(kt * 4 + kq) << 3];
          acc0 = __builtin_amdgcn_mfma_f32_16x16x32_f16(a, b0, acc0, 0, 0, 0);
          acc1 = __builtin_amdgcn_mfma_f32_16x16x32_f16(a, b1, acc1, 0, 0, 0);
        }
        WAIT_VM0();
        __builtin_amdgcn_sched_barrier(0);   // rule #18: MFMAs must not hoist above the waitcnt
        #pragma unroll
        for (int kt = 0; kt < 16; ++kt) {
          int bo = (8 + kt * 4 + kq) << 3;
          f16x8 b0 = *(const f16x8*)&w0[r16][bo];
          f16x8 b1 = *(const f16x8*)&w0[16 + r16][bo];
          acc0 = __builtin_amdgcn_mfma_f32_16x16x32_f16(ha[kt], b0, acc0, 0, 0, 0);
          acc1 = __builtin_amdgcn_mfma_f32_16x16x32_f16(ha[kt], b1, acc1, 0, 0, 0);
        }
      } else {
        #pragma unroll
        for (int kt = 0; kt < 2; ++kt) {
          f16x8 a  = *(const f16x8*)&curt[arow][(kt * 4 + kq) << 3];
          f16x8 b0 = *(const f16x8*)&w0[r16][(kt * 4 + kq) << 3];
          f16x8 b1 = *(const f16x8*)&w0[16 + r16][(kt * 4 + kq) << 3];
          acc0 = __builtin_amdgcn_mfma_f32_16x16x32_f16(a, b0, acc0, 0, 0, 0);
          acc1 = __builtin_amdgcn_mfma_f32_16x16x32_f16(a, b1, acc1, 0, 0, 0);
        }
      }
      float bi0 = bias0[r16], bi1 = bias0[16 + r16];
      _Float16* hb = h0buf + (size_t)(t & 1) * BB * HH + (size_t)(Rg + Rw + kq * 4) * HH + U0 + ulane;
      #pragma unroll
      for (int rr = 0; rr < 4; ++rr) {
        float p0 = acc0[rr] + bi0, p1 = acc1[rr] + bi1;
        float q0 = __shfl_xor(p0, 8), q1 = __shfl_xor(p1, 8);
        float iv = lo8 ? p0 : q0, fv = lo8 ? q0 : p0;
        float gv = lo8 ? p1 : q1, ov = lo8 ? q1 : p1;
        int row = Rw + kq * 4 + rr;
        float cold = (t == 0) ? 0.f : c0s[row][ulane];
        float cn = sigf(fv) * cold + sigf(iv) * tanhfast(gv);
        float hn = sigf(ov) * tanhfast(cn);
        if (lo8) {
          c0s[row][ulane] = cn;
          unsigned hv = (unsigned)__builtin_bit_cast(unsigned short, (_Float16)hn);
          STH(hb, hv, rr * 1024);   // rr advances one row = HH*2B = 1024B
        }
      }
    }
    group_barrier(cnt, ++bticket);   // h0[t] visible group-wide

    // ---- phase 1: layer1 + output ----
    {
      f32x4 acc0 = {0,0,0,0}, acc1 = {0,0,0,0};
      const int arow = Rw + r16;
      f16x8 ha[16];
      {
        const _Float16* h0c = h0buf + (size_t)(t & 1) * BB * HH + (size_t)(Rg + arow) * HH + kq * 8;
        #pragma unroll
        for (int kt = 0; kt < 16; ++kt) LDX4(ha[kt], h0c, kt * 64);
        WAIT_VM0();
        __builtin_amdgcn_sched_barrier(0);
        #pragma unroll
        for (int kt = 0; kt < 16; ++kt) {
          int bo = (kt * 4 + kq) << 3;
          f16x8 b0 = *(const f16x8*)&w1[r16][bo];
          f16x8 b1 = *(const f16x8*)&w1[16 + r16][bo];
          acc0 = __builtin_amdgcn_mfma_f32_16x16x32_f16(ha[kt], b0, acc0, 0, 0, 0);
          acc1 = __builtin_amdgcn_mfma_f32_16x16x32_f16(ha[kt], b1, acc1, 0, 0, 0);
        }
      }
      if (t > 0) {
        const _Float16* h1p = h1buf + (size_t)((t - 1) & 1) * BB * HH + (size_t)(Rg + arow) * HH + kq * 8;
        #pragma unroll
        for (int kt = 0; kt < 16; ++kt) LDX4(ha[kt], h1p, kt * 64);
        WAIT_VM0();
        __builtin_amdgcn_sched_barrier(0);
        #pragma unroll
        for (int kt = 0; kt < 16; ++kt) {
          int bo = (64 + kt * 4 + kq) << 3;
          f16x8 b0 = *(const f16x8*)&w1[r16][bo];
          f16x8 b1 = *(const f16x8*)&w1[16 + r16][bo];
          acc0 = __builtin_amdgcn_mfma_f32_16x16x32_f16(ha[kt], b0, acc0, 0, 0, 0);
          acc1 = __builtin_amdgcn_mfma_f32_16x16x32_f16(ha[kt], b1, acc1, 0, 0, 0);
        }
      }
      float bi0 = bias1[r16], bi1 = bias1[16 + r16];
      _Float16* hb = h1buf + (size_t)(t & 1) * BB * HH + (size_t)(Rg + Rw + kq * 4) * HH + U0 + ulane;
      #pragma unroll
      for (int rr = 0; rr < 4; ++rr) {
        float p0 = acc0[rr] + bi0, p1 = acc1[rr] + bi1;
        float q0 = __shfl_xor(p0, 8), q1 = __shfl_xor(p1, 8);
        float iv = lo8 ? p0 : q0, fv = lo8 ? q0 : p0;
        float gv = lo8 ? p1 : q1, ov = lo8 ? q1 : p1;
        int row = Rw + kq * 4 + rr;
        float cold = (t == 0) ? 0.f : c1s[row][ulane];
        float cn = sigf(fv) * cold + sigf(iv) * tanhfast(gv);
        float hn = sigf(ov) * tanhfast(cn);
        float pv = 0.f;
        if (lo8) {
          c1s[row][ulane] = cn;
          unsigned hv = (unsigned)__builtin_bit_cast(unsigned short, (_Float16)hn);
          STH(hb, hv, rr * 1024);
          pv = hn * wouts[ulane];
        }
        pv += __shfl_xor(pv, 1);
        pv += __shfl_xor(pv, 2);
        pv += __shfl_xor(pv, 4);
        if ((lane & 15) == 0) {
          atomicAdd(&out[(size_t)(Rg + row) * SS + t], pv + (shard == 0 ? boutv : 0.f));
        }
      }
    }
    group_barrier(cnt, ++bticket);   // h1[t] + out[t] visible
  }
}

extern "C" void kernel_launch(void* const* d_in, const int* in_sizes, int n_in,
                              void* d_out, int out_size, void* d_ws, size_t ws_size,
                              hipStream_t stream) {
  const float* x    = (const float*)d_in[0];
  const float* Wih0 = (const float*)d_in[1];
  const float* Whh0 = (const float*)d_in[2];
  const float* bih0 = (const float*)d_in[3];
  const float* bhh0 = (const float*)d_in[4];
  const float* Wih1 = (const float*)d_in[5];
  const float* Whh1 = (const float*)d_in[6];
  const float* bih1 = (const float*)d_in[7];
  const float* bhh1 = (const float*)d_in[8];
  const float* Wout = (const float*)d_in[9];
  const float* bout = (const float*)d_in[10];
  float* out = (float*)d_out;

  // workspace layout: h0buf (1MB) | h1buf (1MB) | barrier counters (1KB)
  const size_t hbytes = (size_t)2 * BB * HH * sizeof(_Float16);
  _Float16* h0buf = (_Float16*)d_ws;
  _Float16* h1buf = (_Float16*)((char*)d_ws + hbytes);
  unsigned* barcnt = (unsigned*)((char*)d_ws + 2 * hbytes);

  // out is atomically accumulated; barrier counters are monotonic from 0.
  hipMemsetAsync(d_out, 0, (size_t)out_size * sizeof(float), stream);
  hipMemsetAsync(barcnt, 0, 4 * 64 * sizeof(unsigned), stream);

  // Cooperative launch: guarantees all 256 wgs co-resident (or errors), so the
  // inter-wg spin barriers cannot deadlock-hang the device.
  void* args[] = {
      (void*)&x, (void*)&Wih0, (void*)&Whh0, (void*)&bih0, (void*)&bhh0,
      (void*)&Wih1, (void*)&Whh1, (void*)&bih1, (void*)&bhh1,
      (void*)&Wout, (void*)&bout, (void*)&out, (void*)&h0buf, (void*)&h1buf,
      (void*)&barcnt};
  hipLaunchCooperativeKernel((const void*)lstm_persist, dim3(256), dim3(512),
                             args, 0, stream);
}